// Round 1
// baseline (8697.189 us; speedup 1.0000x reference)
//
#include <hip/hip_runtime.h>

#define NS 1024
#define NH 64
#define NB 16384

// ---- XLA-CPU fp32 op clones (no FP contraction: __fmul_rn/__fadd_rn) ----

// Clone of XLA GenerateVF32Exp (Cephes/Eigen pexp, as in llvm_ir_runtime.cc)
__device__ __forceinline__ float xexp(float x) {
  x = fminf(x, 88.3762626647950f);
  x = fmaxf(x, -88.3762626647949f);
  float fx = floorf(__fadd_rn(__fmul_rn(x, 1.44269504088896341f), 0.5f));
  x = __fsub_rn(x, __fmul_rn(fx, 0.693359375f));
  x = __fsub_rn(x, __fmul_rn(fx, -2.12194440e-4f));
  float z = __fmul_rn(x, x);
  float y = 1.9875691500e-4f;
  y = __fadd_rn(__fmul_rn(y, x), 1.3981999507e-3f);
  y = __fadd_rn(__fmul_rn(y, x), 8.3334519073e-3f);
  y = __fadd_rn(__fmul_rn(y, x), 4.1665795894e-2f);
  y = __fadd_rn(__fmul_rn(y, x), 1.6666665459e-1f);
  y = __fadd_rn(__fmul_rn(y, x), 5.0000001201e-1f);
  y = __fadd_rn(__fmul_rn(y, z), x);
  y = __fadd_rn(y, 1.0f);
  int n = (int)fx;                       // fx is integral, small range here
  float p2n = __int_as_float((n + 127) << 23);
  return __fmul_rn(y, p2n);
}

// XLA logistic expansion: 1 / (1 + exp(-x)), IEEE divide
__device__ __forceinline__ float xsigmoid(float x) {
  float e = xexp(-x);
  return __fdiv_rn(1.0f, __fadd_rn(1.0f, e));
}

// Clone of XLA EmitFastTanh (Eigen ptanh rational approximation)
__device__ __forceinline__ float xtanh(float x) {
  float xc = fminf(fmaxf(x, -7.90531110763549805f), 7.90531110763549805f);
  float s = __fmul_rn(xc, xc);
  float p = -2.76076847742355e-16f;
  p = __fadd_rn(__fmul_rn(p, s), 2.00018790482477e-13f);
  p = __fadd_rn(__fmul_rn(p, s), -8.60467152213735e-11f);
  p = __fadd_rn(__fmul_rn(p, s), 5.12229709037114e-08f);
  p = __fadd_rn(__fmul_rn(p, s), 1.48572235717979e-05f);
  p = __fadd_rn(__fmul_rn(p, s), 6.37261928875436e-04f);
  p = __fadd_rn(__fmul_rn(p, s), 4.89352455891786e-03f);
  float num = __fmul_rn(xc, p);
  float q = 1.19825839466702e-06f;
  q = __fadd_rn(__fmul_rn(q, s), 1.18534705686654e-04f);
  q = __fadd_rn(__fmul_rn(q, s), 2.26843463243900e-03f);
  q = __fadd_rn(__fmul_rn(q, s), 4.89352518554385e-03f);
  float rat = __fdiv_rn(num, q);
  return (fabsf(x) < 0.0004f) ? x : rat;
}

// One wave (64 lanes) per batch row. Lane j owns hidden unit j.
// w_hh rows for unit j (gates r,z,n) are resident in VGPRs (192 floats).
// h is broadcast each step via a per-wave LDS buffer, read as uniform float4.
__global__ __launch_bounds__(256, 2) void gru_sample_kernel(
    const float* __restrict__ u, const float* __restrict__ w_ih,
    const float* __restrict__ w_hh, const float* __restrict__ b_ih,
    const float* __restrict__ b_hh, const float* __restrict__ head_w,
    const float* __restrict__ head_b, int* __restrict__ out) {
  const int lane = threadIdx.x & 63;
  const int wv = threadIdx.x >> 6;
  const int row = blockIdx.x * 4 + wv;
  if (row >= NB) return;

  __shared__ float hbuf[4][NH];

  // Per-lane weight rows: w_hh[(g*64+lane)][k], k = 0..63
  float w_r[NH], w_z[NH], w_n[NH];
#pragma unroll
  for (int kq = 0; kq < 16; ++kq) {
    float4 a = *(const float4*)&w_hh[(size_t)(lane)*NH + kq * 4];
    float4 b = *(const float4*)&w_hh[(size_t)(64 + lane) * NH + kq * 4];
    float4 c = *(const float4*)&w_hh[(size_t)(128 + lane) * NH + kq * 4];
    w_r[kq * 4 + 0] = a.x; w_r[kq * 4 + 1] = a.y; w_r[kq * 4 + 2] = a.z; w_r[kq * 4 + 3] = a.w;
    w_z[kq * 4 + 0] = b.x; w_z[kq * 4 + 1] = b.y; w_z[kq * 4 + 2] = b.z; w_z[kq * 4 + 3] = b.w;
    w_n[kq * 4 + 0] = c.x; w_n[kq * 4 + 1] = c.y; w_n[kq * 4 + 2] = c.z; w_n[kq * 4 + 3] = c.w;
  }
  const float bih_r = b_ih[lane], bih_z = b_ih[64 + lane], bih_n = b_ih[128 + lane];
  const float bhh_r = b_hh[lane], bhh_z = b_hh[64 + lane], bhh_n = b_hh[128 + lane];
  const float wih_r = w_ih[lane], wih_z = w_ih[64 + lane], wih_n = w_ih[128 + lane];
  const float hw = head_w[lane];
  const float hb = head_b[0];

  const float* urow = u + (size_t)row * NS;
  int* orow = out + (size_t)row * NS;

  float h = 0.0f, prev = 0.0f;
  hbuf[wv][lane] = 0.0f;  // h0 = 0 (same-wave LDS, no barrier needed)

  float u_cur = urow[lane];  // chunk 0
  for (int c = 0; c < 16; ++c) {
    float u_next = (c < 15) ? urow[(c + 1) * 64 + lane] : 0.0f;
    float mybit = 0.0f;
    for (int tt = 0; tt < 64; ++tt) {
      // gh = h @ w_hh.T : Eigen gebp clone — sequential-k FMA from 0
      float acc_r = 0.0f, acc_z = 0.0f, acc_n = 0.0f;
#pragma unroll
      for (int kq = 0; kq < 16; ++kq) {
        float4 hv = *(const float4*)&hbuf[wv][kq * 4];  // uniform b128 broadcast
        acc_r = fmaf(hv.x, w_r[kq * 4 + 0], acc_r);
        acc_r = fmaf(hv.y, w_r[kq * 4 + 1], acc_r);
        acc_r = fmaf(hv.z, w_r[kq * 4 + 2], acc_r);
        acc_r = fmaf(hv.w, w_r[kq * 4 + 3], acc_r);
        acc_z = fmaf(hv.x, w_z[kq * 4 + 0], acc_z);
        acc_z = fmaf(hv.y, w_z[kq * 4 + 1], acc_z);
        acc_z = fmaf(hv.z, w_z[kq * 4 + 2], acc_z);
        acc_z = fmaf(hv.w, w_z[kq * 4 + 3], acc_z);
        acc_n = fmaf(hv.x, w_n[kq * 4 + 0], acc_n);
        acc_n = fmaf(hv.y, w_n[kq * 4 + 1], acc_n);
        acc_n = fmaf(hv.z, w_n[kq * 4 + 2], acc_n);
        acc_n = fmaf(hv.w, w_n[kq * 4 + 3], acc_n);
      }
      // bias adds + gate math: exact reference association, no contraction
      float gh_r = __fadd_rn(acc_r, bhh_r);
      float gh_z = __fadd_rn(acc_z, bhh_z);
      float gh_n = __fadd_rn(acc_n, bhh_n);
      float gx_r = __fadd_rn(__fmul_rn(prev, wih_r), bih_r);
      float gx_z = __fadd_rn(__fmul_rn(prev, wih_z), bih_z);
      float gx_n = __fadd_rn(__fmul_rn(prev, wih_n), bih_n);
      float r = xsigmoid(__fadd_rn(gx_r, gh_r));
      float z = xsigmoid(__fadd_rn(gx_z, gh_z));
      float n = xtanh(__fadd_rn(gx_n, __fmul_rn(r, gh_n)));
      float hn = __fadd_rn(__fmul_rn(__fsub_rn(1.0f, z), n), __fmul_rn(z, h));
      h = hn;
      hbuf[wv][lane] = h;  // for next step's matvec

      // head gemv clone: width-16 chunks (mul + ordered adds), halving tree
      float P = __fmul_rn(h, hw);
      float s = __fadd_rn(P, __shfl(P, lane + 16));
      s = __fadd_rn(s, __shfl(P, lane + 32));
      s = __fadd_rn(s, __shfl(P, lane + 48));
      s = __fadd_rn(s, __shfl(s, lane + 8));
      s = __fadd_rn(s, __shfl(s, lane + 4));
      s = __fadd_rn(s, __shfl(s, lane + 2));
      s = __fadd_rn(s, __shfl(s, lane + 1));
      float logit = __fadd_rn(__shfl(s, 0), hb);
      float p = xsigmoid(logit);

      float u_t = __shfl(u_cur, tt);
      float bit = (u_t < p) ? 1.0f : 0.0f;
      prev = bit;
      mybit = (lane == tt) ? bit : mybit;
    }
    orow[c * 64 + lane] = (int)mybit;  // coalesced per 64-step chunk
    u_cur = u_next;
  }
}

extern "C" void kernel_launch(void* const* d_in, const int* in_sizes, int n_in,
                              void* d_out, int out_size, void* d_ws, size_t ws_size,
                              hipStream_t stream) {
  const float* u = (const float*)d_in[0];
  const float* w_ih = (const float*)d_in[1];
  const float* w_hh = (const float*)d_in[2];
  const float* b_ih = (const float*)d_in[3];
  const float* b_hh = (const float*)d_in[4];
  const float* head_w = (const float*)d_in[5];
  const float* head_b = (const float*)d_in[6];
  int* out = (int*)d_out;
  dim3 grid(NB / 4), block(256);
  gru_sample_kernel<<<grid, block, 0, stream>>>(u, w_ih, w_hh, b_ih, b_hh,
                                                head_w, head_b, out);
}